// Round 2
// baseline (327.267 us; speedup 1.0000x reference)
//
#include <hip/hip_runtime.h>
#include <hip/hip_bf16.h>
#include <cstdint>
#include <cstddef>

typedef __hip_bfloat16 bf16;
typedef float  floatx4 __attribute__((ext_vector_type(4)));
typedef __bf16 bf16x8  __attribute__((ext_vector_type(8)));

typedef __attribute__((address_space(1))) void as1_void;
typedef __attribute__((address_space(3))) void as3_void;

constexpr int Bn = 4, Ln = 2048, Cn = 1024;

__device__ __forceinline__ void store_one(float* p, float v) { *p = v; }
__device__ __forceinline__ void store_one(bf16*  p, float v) { *p = __float2bfloat16(v); }

// ---------------------------------------------------------------------------
// 256x256-tile, BK=64, 8-wave (2Mx4N), 8-phase counted-vmcnt GEMM core.
// R1 verified: SQ_LDS_BANK_CONFLICT == 0 (T2 swizzle works); per-CU MFMA
// efficiency ~48% (g4 heavy block 268 MFLOP in 56.6us).
// R2: core refactored to take kbeg/kend (split-K) and leave acc in regs so
// g4 can attach writer/finisher epilogues. smem hoisted to kernel scope
// (double-call in g4 j0 would otherwise double-allocate LDS).
// ---------------------------------------------------------------------------
#define BAR()    asm volatile("s_barrier" ::: "memory")
#define VMCNT2() asm volatile("s_waitcnt vmcnt(2)" ::: "memory")
#define VMCNT0() asm volatile("s_waitcnt vmcnt(0)" ::: "memory")
#define SCHEDB() __builtin_amdgcn_sched_barrier(0)
#define STAGE(gp, off) \
    __builtin_amdgcn_global_load_lds((const as1_void*)(gp), (as3_void*)(smem + (off)), 16, 0, 0)

__device__ __forceinline__ void gemm256_core(
    char* __restrict__ smem,
    const bf16* __restrict__ A, const bf16* __restrict__ B,
    int m0, int n0, int kbeg, int kend, int lda, int ldb,
    floatx4 (&acc)[8][4])
{
    const int tid  = threadIdx.x;
    const int lane = tid & 63;
    const int quad = lane >> 4;
    const int lr   = lane & 15;
    const int wave = tid >> 6;
    const int wm   = (wave >> 2) * 128;   // 2 waves along M
    const int wn   = (wave & 3) * 64;     // 4 waves along N

#pragma unroll
    for (int i = 0; i < 8; ++i)
#pragma unroll
        for (int j = 0; j < 4; ++j) { floatx4 z = {0.f, 0.f, 0.f, 0.f}; acc[i][j] = z; }

    // staging: pre-swizzled global source, linear LDS dest (T2 + m104 rule)
    const int srow = tid >> 3;                    // 0..63 within a unit
    const int sx   = (tid & 7) ^ (srow & 7);      // inverse-swizzled k-slot
    const bf16* gA = A + (size_t)(m0 + srow) * lda + sx * 8 + kbeg;
    const bf16* gB = B + (size_t)(n0 + srow) * ldb + sx * 8 + kbeg;
    const int wuni = __builtin_amdgcn_readfirstlane((tid & 0x1C0) * 16); // wave*1024

    // read-side fragment offsets (elements)
    const int aoff = (wm + lr) * 64;
    const int boff = (wn + lr) * 64;
    const int s0   = (quad ^ (lr & 7)) * 8;       // kk=0 slot; kk=1 is s0^32

    const int NT = (kend - kbeg) >> 6;

    // prologue: tile 0 -> buf0; B0-3,A0,A2 (read at phase A) then A1,A3
    // (read at phase B). vmcnt(2) completes the first six.
    STAGE(gB,             32768 + 0 * 8192 + wuni);
    STAGE(gB + 64  * ldb, 32768 + 1 * 8192 + wuni);
    STAGE(gB + 128 * ldb, 32768 + 2 * 8192 + wuni);
    STAGE(gB + 192 * ldb, 32768 + 3 * 8192 + wuni);
    STAGE(gA,                     0 * 8192 + wuni);
    STAGE(gA + 128 * lda,         2 * 8192 + wuni);
    STAGE(gA + 64  * lda,         1 * 8192 + wuni);
    STAGE(gA + 192 * lda,         3 * 8192 + wuni);
    VMCNT2();
    BAR();

#define LDA4(MB, SK) do { _Pragma("unroll") for (int ii = 0; ii < 4; ++ii) \
        a[ii] = *(const bf16x8*)(As + aoff + ((MB) * 4 + ii) * 1024 + (SK)); } while (0)
#define LDB4(SK) do { _Pragma("unroll") for (int nn = 0; nn < 4; ++nn) \
        b[nn] = *(const bf16x8*)(Bs + boff + nn * 1024 + (SK)); } while (0)
#define MFMA16(MB) do { _Pragma("unroll") for (int ii = 0; ii < 4; ++ii) { \
        _Pragma("unroll") for (int nn = 0; nn < 4; ++nn) \
            acc[(MB) * 4 + ii][nn] = __builtin_amdgcn_mfma_f32_16x16x32_bf16( \
                a[ii], b[nn], acc[(MB) * 4 + ii][nn], 0, 0, 0); } } while (0)

    for (int t = 0; t < NT; ++t) {
        const bf16* As = (const bf16*)(smem + (t & 1) * 65536);
        const bf16* Bs = (const bf16*)(smem + (t & 1) * 65536 + 32768);
        const int  wl  = ((t + 1) & 1) * 65536;
        const int  kn  = (t + 1) << 6;            // relative to gA/gB (kbeg folded)
        const bool more = (t + 1 < NT);
        bf16x8 a[4], b[4];

        // ---- phase A: mi0-3, kk0 ----
        LDB4(s0);
        LDA4(0, s0);
        if (more) {
            STAGE(gB + kn,            wl + 32768 + 0 * 8192 + wuni);
            STAGE(gB + kn + 64 * ldb, wl + 32768 + 1 * 8192 + wuni);
        }
        BAR(); SCHEDB();
        __builtin_amdgcn_s_setprio(1);
        MFMA16(0);
        __builtin_amdgcn_s_setprio(0);
        SCHEDB();
        if (more) VMCNT2(); else VMCNT0();   // A1,A3 of tile t now resident
        BAR();

        // ---- phase B: mi4-7, kk0 ----
        LDA4(1, s0);
        if (more) {
            STAGE(gB + kn + 128 * ldb, wl + 32768 + 2 * 8192 + wuni);
            STAGE(gB + kn + 192 * ldb, wl + 32768 + 3 * 8192 + wuni);
        }
        BAR(); SCHEDB();
        __builtin_amdgcn_s_setprio(1);
        MFMA16(1);
        __builtin_amdgcn_s_setprio(0);
        SCHEDB();
        BAR();

        // ---- phase C: mi0-3, kk1 ----
        LDB4(s0 ^ 32);
        LDA4(0, s0 ^ 32);
        if (more) {
            STAGE(gA + kn,             wl + 0 * 8192 + wuni);
            STAGE(gA + kn + 128 * lda, wl + 2 * 8192 + wuni);
        }
        BAR(); SCHEDB();
        __builtin_amdgcn_s_setprio(1);
        MFMA16(0);
        __builtin_amdgcn_s_setprio(0);
        SCHEDB();
        BAR();

        // ---- phase D: mi4-7, kk1 ----
        LDA4(1, s0 ^ 32);
        if (more) {
            STAGE(gA + kn + 64  * lda, wl + 1 * 8192 + wuni);
            STAGE(gA + kn + 192 * lda, wl + 3 * 8192 + wuni);
        }
        BAR(); SCHEDB();
        __builtin_amdgcn_s_setprio(1);
        MFMA16(1);
        __builtin_amdgcn_s_setprio(0);
        SCHEDB();
        if (more) VMCNT2();                  // B0-3,A0,A2 of tile t+1 resident
        BAR();
    }
#undef LDA4
#undef LDB4
#undef MFMA16
}

template <typename OutT>
__device__ __forceinline__ void gemm256(
    char* __restrict__ smem,
    const bf16* __restrict__ A, const bf16* __restrict__ B, OutT* __restrict__ C,
    int m0, int n0, int kbeg, int kend, int lda, int ldb, int ldc, float cscale)
{
    floatx4 acc[8][4];
    gemm256_core(smem, A, B, m0, n0, kbeg, kend, lda, ldb, acc);

    const int lane = threadIdx.x & 63;
    const int quad = lane >> 4;
    const int lr   = lane & 15;
    const int wave = threadIdx.x >> 6;
    const int wm   = (wave >> 2) * 128;
    const int wn   = (wave & 3) * 64;

    // C/D layout col=lane&15, row=quad*4+r (m89-verified)
#pragma unroll
    for (int mi = 0; mi < 8; ++mi) {
        const int row = m0 + wm + mi * 16 + quad * 4;
#pragma unroll
        for (int n = 0; n < 4; ++n) {
            const int col = n0 + wn + n * 16 + lr;
            OutT* cp = C + (size_t)row * ldc + col;
#pragma unroll
            for (int r = 0; r < 4; ++r)
                store_one(cp + (size_t)r * ldc, acc[mi][n][r] * cscale);
        }
    }
}

// ---------------------------------------------------------------------------
// g1: QK = Xb . Wqkb^T  (8192x2048, K=1024) -> 32x8 = 256 blocks (1 full wave)
// ---------------------------------------------------------------------------
__global__ __launch_bounds__(512, 2)
void g1_qk(const bf16* __restrict__ Xb, const bf16* __restrict__ Wqkb,
           bf16* __restrict__ QK)
{
    __shared__ __align__(16) char smem[131072];
    const int i = blockIdx.x;
    const int j = i >> 3;
    const int mt = (i & 7) * 4 + (j & 3);
    const int nt = j >> 2;
    gemm256<bf16>(smem, Xb, Wqkb, QK, mt * 256, nt * 256, 0, 1024, 1024, 1024, 2048, 1.0f);
}

// ---------------------------------------------------------------------------
// g2: blocks [0,144)  -> S = (Q.K^T)/32, triangular 256-tiles, 36/batch.
//     blocks [144,160) -> W2 = Wo.Wv (1024^2, K=1024).
// ---------------------------------------------------------------------------
__global__ __launch_bounds__(512, 2)
void g2_s_w2(const bf16* __restrict__ QK, const bf16* __restrict__ Wob,
             const bf16* __restrict__ WvT, bf16* __restrict__ S,
             bf16* __restrict__ W2)
{
    __shared__ __align__(16) char smem[131072];
    const int i = blockIdx.x;
    if (i < 144) {
        const int b = (i & 7) >> 1;
        const int t = (i >> 3) * 2 + (i & 1);        // 0..35
        int ti = (int)((sqrtf(8.f * t + 1.f) - 1.f) * 0.5f);
        while ((ti + 1) * (ti + 2) / 2 <= t) ++ti;
        while (ti * (ti + 1) / 2 > t) --ti;
        const int tj = t - ti * (ti + 1) / 2;
        const bf16* Aq = QK + (size_t)b * Ln * 2048;
        const bf16* Bk = Aq + 1024;
        bf16* Sb = S + (size_t)b * Ln * Ln;
        gemm256<bf16>(smem, Aq, Bk, Sb, ti * 256, tj * 256, 0, 1024, 2048, 2048, Ln, 0.03125f);
    } else {
        const int j = i - 144;
        gemm256<bf16>(smem, Wob, WvT, W2, (j & 3) * 256, (j >> 2) * 256, 0, 1024, 1024, 1024, 1024, 1.0f);
    }
}

// ---------------------------------------------------------------------------
// softmax rows (one wave per row, no barriers) — fused into g3.
// ---------------------------------------------------------------------------
__device__ __forceinline__ float waveMax(float x) {
#pragma unroll
    for (int o = 32; o > 0; o >>= 1) x = fmaxf(x, __shfl_xor(x, o, 64));
    return x;
}
__device__ __forceinline__ float waveSum(float x) {
#pragma unroll
    for (int o = 32; o > 0; o >>= 1) x += __shfl_xor(x, o, 64);
    return x;
}

__device__ void softmax_rows(bf16* __restrict__ S, int row0)
{
    const int wave = threadIdx.x >> 6, lane = threadIdx.x & 63;
    for (int it8 = 0; it8 < 8; ++it8) {
        const int row = row0 + wave * 8 + it8;       // 0..8191 = b*L + q
        const int q = row & (Ln - 1);
        bf16* Srow = S + (size_t)row * Ln;
        const int kmax = ((q >> 7) + 1) << 7;
        const int nv = (kmax + 511) >> 9;            // 1..4 chunks of 512 cols
        float x[4][8];
        float m = -1e30f;
        for (int it = 0; it < nv; ++it) {
            int c0 = it * 512 + lane * 8;
            bf16x8 v = *(const bf16x8*)(Srow + c0);
#pragma unroll
            for (int e = 0; e < 8; ++e) {
                float f = (float)v[e];
                f = (c0 + e <= q) ? f : -1e30f;
                x[it][e] = f;
                m = fmaxf(m, f);
            }
        }
        m = waveMax(m);
        float s = 0.f;
        for (int it = 0; it < nv; ++it)
#pragma unroll
            for (int e = 0; e < 8; ++e) {
                float ex = (x[it][e] > -1e29f) ? __expf(x[it][e] - m) : 0.f;
                x[it][e] = ex;
                s += ex;
            }
        s = waveSum(s);
        const float inv = 1.f / s;
        for (int it = 0; it < nv; ++it) {
            bf16x8 o;
#pragma unroll
            for (int e = 0; e < 8; ++e) o[e] = (__bf16)(x[it][e] * inv);
            *(bf16x8*)(Srow + it * 512 + lane * 8) = o;
        }
    }
}

// ---------------------------------------------------------------------------
// g3: blocks [0,128)   -> VWT = W2 . Xb^T (1024x8192, ldc 8192); needs W2.
//     blocks [128,256) -> causal softmax on S (64 rows/block); needs all S.
// ---------------------------------------------------------------------------
__global__ __launch_bounds__(512, 2)
void g3_vwt_sm(const bf16* __restrict__ W2, const bf16* __restrict__ Xb,
               bf16* __restrict__ VWT, bf16* __restrict__ S)
{
    __shared__ __align__(16) char smem[131072];
    const int i = blockIdx.x;
    if (i < 128) {
        const int j = i >> 3;
        const int nt = (i & 7) * 4 + (j & 3);        // 0..31 (Xb panel L2-local)
        const int mt = j >> 2;                       // 0..3
        gemm256<bf16>(smem, W2, Xb, VWT, mt * 256, nt * 256, 0, 1024, 1024, 1024, 8192, 1.0f);
    } else {
        softmax_rows(S, (i - 128) * 64);
    }
}

// ---------------------------------------------------------------------------
// g4: out = P . VW (fp32 out), causal K = (mt+1)*256 — R2: balanced split-K.
// 576 K-units (unit = K=256 slab of a 256^2 tile) -> 224 blocks of <=3 units
// (max K=768 ~ 21us), all co-resident (224 < 256 CUs, 1 blk/CU).
// Job table per (b,nt), 14 blocks:
//   j0: mt0 [0,256) + mt1 [0,512) both direct (two full tiles, 3u)
//   j1: mt2 [0,768) direct (3u)
//   mt3..mt7 split; chunk 0 = designated finisher (spins on ticket, then
//   acc + sum(partials) -> out); other chunks write fp32 partials + ticket.
// Partials live in the dead Xb+QK region [0,48MiB) (Xb dead after g3, QK
// after g2); tickets at ws+106MiB, zeroed by cast_all each iteration.
// Deadlock-safe: all 224 blocks resident => writers always progress.
// rocprof replay-safe: stale tickets only short-circuit the spin; partials
// from the prior identical run hold the same values.
// ---------------------------------------------------------------------------
__device__ const short jb_mt[14]   = {0, 2, 3, 3,   4, 4,   5, 5,   6, 6,    6,    7, 7,    7};
__device__ const short jb_kb[14]   = {0, 0, 0, 512, 0, 768, 0, 768, 0, 768,  1280, 0, 768,  1536};
__device__ const short jb_ke[14]   = {0, 768, 512, 1024, 768, 1280, 768, 1536, 768, 1280, 1792, 768, 1536, 2048};
__device__ const short jb_role[14] = {0, 0, 2, 1,   2, 1,   2, 1,   2, 1,    1,    2, 1,    1};  // 0 direct,1 writer,2 finisher
__device__ const short jb_cid[14]  = {0, 0, 0, 1,   0, 1,   0, 1,   0, 1,    2,    0, 1,    2};
__device__ const short jb_nch[14]  = {1, 1, 2, 2,   2, 2,   2, 2,   3, 3,    3,    3, 3,    3};

__global__ __launch_bounds__(512, 2)
void g4_out(const bf16* __restrict__ P, const bf16* __restrict__ VWT,
            float* __restrict__ out, float* __restrict__ paux,
            int* __restrict__ tickets)
{
    __shared__ __align__(16) char smem[131072];
    const int i = blockIdx.x;                        // 224
    const int r = i & 7;                             // xcd = 2b+p
    const int b = r >> 1, p = r & 1;
    const int q = i >> 3;                            // 0..27
    const int nt = p * 2 + (q & 1);
    const int j = q >> 1;                            // 0..13

    const bf16* Pp = P + (size_t)b * Ln * Ln;
    const bf16* Bv = VWT + (size_t)b * Ln;
    float* Co = out + (size_t)b * Ln * Cn;
    const int n0 = nt * 256;

    if (j == 0) {
        // two full small tiles, direct store
        gemm256<float>(smem, Pp, Bv, Co, 0,   n0, 0, 256, Ln, 8192, Cn, 1.0f);
        gemm256<float>(smem, Pp, Bv, Co, 256, n0, 0, 512, Ln, 8192, Cn, 1.0f);
        return;
    }

    const int mt   = jb_mt[j];
    const int kb   = jb_kb[j];
    const int ke   = jb_ke[j];
    const int role = jb_role[j];
    const int m0   = mt * 256;

    if (role == 0) {
        gemm256<float>(smem, Pp, Bv, Co, m0, n0, kb, ke, Ln, 8192, Cn, 1.0f);
        return;
    }

    floatx4 acc[8][4];
    gemm256_core(smem, Pp, Bv, m0, n0, kb, ke, Ln, 8192, acc);

    const int tid  = threadIdx.x;
    const int lane = tid & 63;
    const int quad = lane >> 4;
    const int lr   = lane & 15;
    const int wave = tid >> 6;
    const int wm   = (wave >> 2) * 128;
    const int wn   = (wave & 3) * 64;

    const int tred = (b * 4 + nt) * 5 + (mt - 3);    // 0..79
    float* slot0 = paux + ((size_t)(tred * 2) << 16);

    if (role == 1) {
        // writer: store fp32 partial, release ticket
        const int cid = jb_cid[j];
        float* slot = slot0 + ((size_t)(cid - 1) << 16);
#pragma unroll
        for (int mi = 0; mi < 8; ++mi) {
            const int lrow = wm + mi * 16 + quad * 4;
#pragma unroll
            for (int n = 0; n < 4; ++n) {
                const int lcol = wn + n * 16 + lr;
#pragma unroll
                for (int rr = 0; rr < 4; ++rr)
                    slot[(size_t)(lrow + rr) * 256 + lcol] = acc[mi][n][rr];
            }
        }
        __threadfence();
        __syncthreads();
        if (tid == 0)
            __hip_atomic_fetch_add(&tickets[tred], 1, __ATOMIC_RELEASE, __HIP_MEMORY_SCOPE_AGENT);
        return;
    }

    // finisher: wait for writers, then out = acc + sum(partials)
    const int nch = jb_nch[j];
    if (tid == 0) {
        while (__hip_atomic_load(&tickets[tred], __ATOMIC_ACQUIRE, __HIP_MEMORY_SCOPE_AGENT) < nch - 1)
            __builtin_amdgcn_s_sleep(8);
    }
    __syncthreads();
    const float* s1 = slot0 + 65536;
#pragma unroll
    for (int mi = 0; mi < 8; ++mi) {
        const int lrow = wm + mi * 16 + quad * 4;
#pragma unroll
        for (int n = 0; n < 4; ++n) {
            const int lcol = wn + n * 16 + lr;
#pragma unroll
            for (int rr = 0; rr < 4; ++rr) {
                const size_t li = (size_t)(lrow + rr) * 256 + lcol;
                float v = acc[mi][n][rr] + slot0[li];
                if (nch == 3) v += s1[li];
                Co[(size_t)(m0 + lrow + rr) * Cn + n0 + lcol] = v;
            }
        }
    }
}

// ---------------------------------------------------------------------------
// cast_all: blocks [0,11264)    element-wise fp32->bf16 (X, Wqk rows, Wout)
//           blocks [11264,12288) transpose-cast Wv (1024x1024) -> WvT
// blk 0 additionally zeroes the g4 split-K tickets (stream-ordered before g4).
// ---------------------------------------------------------------------------
__global__ __launch_bounds__(256)
void cast_all(const float* __restrict__ X, const float* __restrict__ Wqkv,
              const float* __restrict__ Wo,
              bf16* __restrict__ Xb, bf16* __restrict__ Wqkb,
              bf16* __restrict__ Wob, bf16* __restrict__ WvT,
              int* __restrict__ tickets)
{
    int blk = blockIdx.x;
    if (blk == 0 && threadIdx.x < 128) tickets[threadIdx.x] = 0;
    if (blk < 11264) {
        int i = blk * 256 + threadIdx.x;
        const float* src; bf16* dst; int off;
        if (i < 2097152)                 { src = X;    dst = Xb;   off = i; }
        else if (i < 2097152 + 524288)   { src = Wqkv; dst = Wqkb; off = i - 2097152; }
        else                             { src = Wo;   dst = Wob;  off = i - 2621440; }
        float4 f = ((const float4*)src)[off];
        bf16 o0 = __float2bfloat16(f.x), o1 = __float2bfloat16(f.y);
        bf16 o2 = __float2bfloat16(f.z), o3 = __float2bfloat16(f.w);
        ushort4 u;
        u.x = *(unsigned short*)&o0; u.y = *(unsigned short*)&o1;
        u.z = *(unsigned short*)&o2; u.w = *(unsigned short*)&o3;
        *(ushort4*)(dst + (size_t)off * 4) = u;
    } else {
        __shared__ float t[32][33];
        int tt = blk - 11264;
        int c0 = (tt & 31) * 32;
        int r0 = (tt >> 5) * 32;
        const float* Wv = Wqkv + 2048 * 1024;
        int xcol = threadIdx.x & 31, y0 = threadIdx.x >> 5;
#pragma unroll
        for (int p = 0; p < 4; ++p) {
            int y = y0 + 8 * p;
            t[y][xcol] = Wv[(size_t)(r0 + y) * 1024 + c0 + xcol];
        }
        __syncthreads();
#pragma unroll
        for (int p = 0; p < 4; ++p) {
            int mloc = y0 + 8 * p;
            WvT[(size_t)(c0 + mloc) * 1024 + r0 + xcol] = __float2bfloat16(t[xcol][mloc]);
        }
    }
}

// ---------------------------------------------------------------------------
extern "C" void kernel_launch(void* const* d_in, const int* in_sizes, int n_in,
                              void* d_out, int out_size, void* d_ws, size_t ws_size,
                              hipStream_t stream)
{
    const float* X    = (const float*)d_in[0];   // (B,L,C)
    const float* Wqkv = (const float*)d_in[1];   // (3C,C)
    const float* Wout = (const float*)d_in[2];   // (C,C)
    float* out = (float*)d_out;                  // (B,L,C) fp32

    char* ws = (char*)d_ws;
    const size_t MiB = 1024ull * 1024ull;
    bf16* Xb   = (bf16*)(ws + 0);                // 16 MiB (dead after g3 -> paux)
    bf16* QK   = (bf16*)(ws + 16 * MiB);         // 32 MiB (dead after g2 -> paux)
    bf16* VWT  = (bf16*)(ws + 48 * MiB);         // 16 MiB (1024 x 8192, ld 8192)
    bf16* Sbuf = (bf16*)(ws + 64 * MiB);         // 32 MiB (P in place)
    bf16* Wqkb = (bf16*)(ws + 96 * MiB);         // 4 MiB
    bf16* WvT  = (bf16*)(ws + 100 * MiB);        // 2 MiB
    bf16* Wob  = (bf16*)(ws + 102 * MiB);        // 2 MiB
    bf16* W2   = (bf16*)(ws + 104 * MiB);        // 2 MiB
    float* paux = (float*)(ws + 0);              // 40 MiB over Xb+QK (g4 only)
    int* tickets = (int*)(ws + 106 * MiB);       // 512 B   (total 106 MiB + 4KiB)

    cast_all<<<dim3(12288), 256, 0, stream>>>(X, Wqkv, Wout, Xb, Wqkb, Wob, WvT, tickets);

    g1_qk<<<dim3(256), 512, 0, stream>>>(Xb, Wqkb, QK);

    g2_s_w2<<<dim3(160), 512, 0, stream>>>(QK, Wob, WvT, Sbuf, W2);

    g3_vwt_sm<<<dim3(256), 512, 0, stream>>>(W2, Xb, VWT, Sbuf);

    g4_out<<<dim3(224), 512, 0, stream>>>(Sbuf, VWT, out, paux, tickets);
}

// Round 3
// 239.386 us; speedup vs baseline: 1.3671x; 1.3671x over previous
//
#include <hip/hip_runtime.h>
#include <hip/hip_bf16.h>
#include <cstdint>
#include <cstddef>

typedef __hip_bfloat16 bf16;
typedef float  floatx4 __attribute__((ext_vector_type(4)));
typedef __bf16 bf16x8  __attribute__((ext_vector_type(8)));

typedef __attribute__((address_space(1))) void as1_void;
typedef __attribute__((address_space(3))) void as3_void;

constexpr int Bn = 4, Ln = 2048, Cn = 1024;

__device__ __forceinline__ void store_one(float* p, float v) { *p = v; }
__device__ __forceinline__ void store_one(bf16*  p, float v) { *p = __float2bfloat16(v); }

// ---------------------------------------------------------------------------
// 256x256-tile, BK=64, 8-wave (2Mx4N), 8-phase counted-vmcnt GEMM core.
// R1 verified: SQ_LDS_BANK_CONFLICT == 0 (T2 swizzle works); ~48% per-CU MFMA.
// R2 LESSON (146us, MfmaUtil 5%): partials + __threadfence + ticket spin is
// catastrophic on gfx950 — device-scope fence after 256KB dirty stores forces
// L2 writeback to the cross-XCD coherence point; 112 writers x fence + 80
// pollers = coherence storm. NO intra-kernel cross-block sync. R3 instead
// uses fire-and-forget global_atomic_add_f32 (unsafeAtomicAdd) into a
// pre-zeroed region: no fence, no spin, order-independent fp32 (2 chunks).
// ---------------------------------------------------------------------------
#define BAR()    asm volatile("s_barrier" ::: "memory")
#define VMCNT2() asm volatile("s_waitcnt vmcnt(2)" ::: "memory")
#define VMCNT0() asm volatile("s_waitcnt vmcnt(0)" ::: "memory")
#define SCHEDB() __builtin_amdgcn_sched_barrier(0)
#define STAGE(gp, off) \
    __builtin_amdgcn_global_load_lds((const as1_void*)(gp), (as3_void*)(smem + (off)), 16, 0, 0)

__device__ __forceinline__ void gemm256_core(
    char* __restrict__ smem,
    const bf16* __restrict__ A, const bf16* __restrict__ B,
    int m0, int n0, int kbeg, int kend, int lda, int ldb,
    floatx4 (&acc)[8][4])
{
    const int tid  = threadIdx.x;
    const int lane = tid & 63;
    const int quad = lane >> 4;
    const int lr   = lane & 15;
    const int wave = tid >> 6;
    const int wm   = (wave >> 2) * 128;   // 2 waves along M
    const int wn   = (wave & 3) * 64;     // 4 waves along N

#pragma unroll
    for (int i = 0; i < 8; ++i)
#pragma unroll
        for (int j = 0; j < 4; ++j) { floatx4 z = {0.f, 0.f, 0.f, 0.f}; acc[i][j] = z; }

    // staging: pre-swizzled global source, linear LDS dest (T2 + m104 rule)
    const int srow = tid >> 3;                    // 0..63 within a unit
    const int sx   = (tid & 7) ^ (srow & 7);      // inverse-swizzled k-slot
    const bf16* gA = A + (size_t)(m0 + srow) * lda + sx * 8 + kbeg;
    const bf16* gB = B + (size_t)(n0 + srow) * ldb + sx * 8 + kbeg;
    const int wuni = __builtin_amdgcn_readfirstlane((tid & 0x1C0) * 16); // wave*1024

    // read-side fragment offsets (elements)
    const int aoff = (wm + lr) * 64;
    const int boff = (wn + lr) * 64;
    const int s0   = (quad ^ (lr & 7)) * 8;       // kk=0 slot; kk=1 is s0^32

    const int NT = (kend - kbeg) >> 6;

    // prologue: tile 0 -> buf0; B0-3,A0,A2 (read at phase A) then A1,A3
    // (read at phase B). vmcnt(2) completes the first six.
    STAGE(gB,             32768 + 0 * 8192 + wuni);
    STAGE(gB + 64  * ldb, 32768 + 1 * 8192 + wuni);
    STAGE(gB + 128 * ldb, 32768 + 2 * 8192 + wuni);
    STAGE(gB + 192 * ldb, 32768 + 3 * 8192 + wuni);
    STAGE(gA,                     0 * 8192 + wuni);
    STAGE(gA + 128 * lda,         2 * 8192 + wuni);
    STAGE(gA + 64  * lda,         1 * 8192 + wuni);
    STAGE(gA + 192 * lda,         3 * 8192 + wuni);
    VMCNT2();
    BAR();

#define LDA4(MB, SK) do { _Pragma("unroll") for (int ii = 0; ii < 4; ++ii) \
        a[ii] = *(const bf16x8*)(As + aoff + ((MB) * 4 + ii) * 1024 + (SK)); } while (0)
#define LDB4(SK) do { _Pragma("unroll") for (int nn = 0; nn < 4; ++nn) \
        b[nn] = *(const bf16x8*)(Bs + boff + nn * 1024 + (SK)); } while (0)
#define MFMA16(MB) do { _Pragma("unroll") for (int ii = 0; ii < 4; ++ii) { \
        _Pragma("unroll") for (int nn = 0; nn < 4; ++nn) \
            acc[(MB) * 4 + ii][nn] = __builtin_amdgcn_mfma_f32_16x16x32_bf16( \
                a[ii], b[nn], acc[(MB) * 4 + ii][nn], 0, 0, 0); } } while (0)

    for (int t = 0; t < NT; ++t) {
        const bf16* As = (const bf16*)(smem + (t & 1) * 65536);
        const bf16* Bs = (const bf16*)(smem + (t & 1) * 65536 + 32768);
        const int  wl  = ((t + 1) & 1) * 65536;
        const int  kn  = (t + 1) << 6;            // relative to gA/gB (kbeg folded)
        const bool more = (t + 1 < NT);
        bf16x8 a[4], b[4];

        // ---- phase A: mi0-3, kk0 ----
        LDB4(s0);
        LDA4(0, s0);
        if (more) {
            STAGE(gB + kn,            wl + 32768 + 0 * 8192 + wuni);
            STAGE(gB + kn + 64 * ldb, wl + 32768 + 1 * 8192 + wuni);
        }
        BAR(); SCHEDB();
        __builtin_amdgcn_s_setprio(1);
        MFMA16(0);
        __builtin_amdgcn_s_setprio(0);
        SCHEDB();
        if (more) VMCNT2(); else VMCNT0();   // A1,A3 of tile t now resident
        BAR();

        // ---- phase B: mi4-7, kk0 ----
        LDA4(1, s0);
        if (more) {
            STAGE(gB + kn + 128 * ldb, wl + 32768 + 2 * 8192 + wuni);
            STAGE(gB + kn + 192 * ldb, wl + 32768 + 3 * 8192 + wuni);
        }
        BAR(); SCHEDB();
        __builtin_amdgcn_s_setprio(1);
        MFMA16(1);
        __builtin_amdgcn_s_setprio(0);
        SCHEDB();
        BAR();

        // ---- phase C: mi0-3, kk1 ----
        LDB4(s0 ^ 32);
        LDA4(0, s0 ^ 32);
        if (more) {
            STAGE(gA + kn,             wl + 0 * 8192 + wuni);
            STAGE(gA + kn + 128 * lda, wl + 2 * 8192 + wuni);
        }
        BAR(); SCHEDB();
        __builtin_amdgcn_s_setprio(1);
        MFMA16(0);
        __builtin_amdgcn_s_setprio(0);
        SCHEDB();
        BAR();

        // ---- phase D: mi4-7, kk1 ----
        LDA4(1, s0 ^ 32);
        if (more) {
            STAGE(gA + kn + 64  * lda, wl + 1 * 8192 + wuni);
            STAGE(gA + kn + 192 * lda, wl + 3 * 8192 + wuni);
        }
        BAR(); SCHEDB();
        __builtin_amdgcn_s_setprio(1);
        MFMA16(1);
        __builtin_amdgcn_s_setprio(0);
        SCHEDB();
        if (more) VMCNT2();                  // B0-3,A0,A2 of tile t+1 resident
        BAR();
    }
#undef LDA4
#undef LDB4
#undef MFMA16
}

template <typename OutT>
__device__ __forceinline__ void gemm256(
    char* __restrict__ smem,
    const bf16* __restrict__ A, const bf16* __restrict__ B, OutT* __restrict__ C,
    int m0, int n0, int kbeg, int kend, int lda, int ldb, int ldc, float cscale)
{
    floatx4 acc[8][4];
    gemm256_core(smem, A, B, m0, n0, kbeg, kend, lda, ldb, acc);

    const int lane = threadIdx.x & 63;
    const int quad = lane >> 4;
    const int lr   = lane & 15;
    const int wave = threadIdx.x >> 6;
    const int wm   = (wave >> 2) * 128;
    const int wn   = (wave & 3) * 64;

    // C/D layout col=lane&15, row=quad*4+r (m89-verified)
#pragma unroll
    for (int mi = 0; mi < 8; ++mi) {
        const int row = m0 + wm + mi * 16 + quad * 4;
#pragma unroll
        for (int n = 0; n < 4; ++n) {
            const int col = n0 + wn + n * 16 + lr;
            OutT* cp = C + (size_t)row * ldc + col;
#pragma unroll
            for (int r = 0; r < 4; ++r)
                store_one(cp + (size_t)r * ldc, acc[mi][n][r] * cscale);
        }
    }
}

// ---------------------------------------------------------------------------
// g1: QK = Xb . Wqkb^T  (8192x2048, K=1024) -> 32x8 = 256 blocks (1 full wave)
// ---------------------------------------------------------------------------
__global__ __launch_bounds__(512, 2)
void g1_qk(const bf16* __restrict__ Xb, const bf16* __restrict__ Wqkb,
           bf16* __restrict__ QK)
{
    __shared__ __align__(16) char smem[131072];
    const int i = blockIdx.x;
    const int j = i >> 3;
    const int mt = (i & 7) * 4 + (j & 3);
    const int nt = j >> 2;
    gemm256<bf16>(smem, Xb, Wqkb, QK, mt * 256, nt * 256, 0, 1024, 1024, 1024, 2048, 1.0f);
}

// ---------------------------------------------------------------------------
// g2: blocks [0,144)  -> S = (Q.K^T)/32, triangular 256-tiles, 36/batch.
//     blocks [144,160) -> W2 = Wo.Wv (1024^2, K=1024).
// ---------------------------------------------------------------------------
__global__ __launch_bounds__(512, 2)
void g2_s_w2(const bf16* __restrict__ QK, const bf16* __restrict__ Wob,
             const bf16* __restrict__ WvT, bf16* __restrict__ S,
             bf16* __restrict__ W2)
{
    __shared__ __align__(16) char smem[131072];
    const int i = blockIdx.x;
    if (i < 144) {
        const int b = (i & 7) >> 1;
        const int t = (i >> 3) * 2 + (i & 1);        // 0..35
        int ti = (int)((sqrtf(8.f * t + 1.f) - 1.f) * 0.5f);
        while ((ti + 1) * (ti + 2) / 2 <= t) ++ti;
        while (ti * (ti + 1) / 2 > t) --ti;
        const int tj = t - ti * (ti + 1) / 2;
        const bf16* Aq = QK + (size_t)b * Ln * 2048;
        const bf16* Bk = Aq + 1024;
        bf16* Sb = S + (size_t)b * Ln * Ln;
        gemm256<bf16>(smem, Aq, Bk, Sb, ti * 256, tj * 256, 0, 1024, 2048, 2048, Ln, 0.03125f);
    } else {
        const int j = i - 144;
        gemm256<bf16>(smem, Wob, WvT, W2, (j & 3) * 256, (j >> 2) * 256, 0, 1024, 1024, 1024, 1024, 1.0f);
    }
}

// ---------------------------------------------------------------------------
// softmax rows (one wave per row, no barriers) — fused into g3.
// ---------------------------------------------------------------------------
__device__ __forceinline__ float waveMax(float x) {
#pragma unroll
    for (int o = 32; o > 0; o >>= 1) x = fmaxf(x, __shfl_xor(x, o, 64));
    return x;
}
__device__ __forceinline__ float waveSum(float x) {
#pragma unroll
    for (int o = 32; o > 0; o >>= 1) x += __shfl_xor(x, o, 64);
    return x;
}

__device__ void softmax_rows(bf16* __restrict__ S, int row0)
{
    const int wave = threadIdx.x >> 6, lane = threadIdx.x & 63;
    for (int it8 = 0; it8 < 8; ++it8) {
        const int row = row0 + wave * 8 + it8;       // 0..8191 = b*L + q
        const int q = row & (Ln - 1);
        bf16* Srow = S + (size_t)row * Ln;
        const int kmax = ((q >> 7) + 1) << 7;
        const int nv = (kmax + 511) >> 9;            // 1..4 chunks of 512 cols
        float x[4][8];
        float m = -1e30f;
        for (int it = 0; it < nv; ++it) {
            int c0 = it * 512 + lane * 8;
            bf16x8 v = *(const bf16x8*)(Srow + c0);
#pragma unroll
            for (int e = 0; e < 8; ++e) {
                float f = (float)v[e];
                f = (c0 + e <= q) ? f : -1e30f;
                x[it][e] = f;
                m = fmaxf(m, f);
            }
        }
        m = waveMax(m);
        float s = 0.f;
        for (int it = 0; it < nv; ++it)
#pragma unroll
            for (int e = 0; e < 8; ++e) {
                float ex = (x[it][e] > -1e29f) ? __expf(x[it][e] - m) : 0.f;
                x[it][e] = ex;
                s += ex;
            }
        s = waveSum(s);
        const float inv = 1.f / s;
        for (int it = 0; it < nv; ++it) {
            bf16x8 o;
#pragma unroll
            for (int e = 0; e < 8; ++e) o[e] = (__bf16)(x[it][e] * inv);
            *(bf16x8*)(Srow + it * 512 + lane * 8) = o;
        }
    }
}

// ---------------------------------------------------------------------------
// g3: blocks [0,128)   -> VWT = W2 . Xb^T (1024x8192, ldc 8192); needs W2.
//     blocks [128,256) -> causal softmax on S (64 rows/block); needs all S.
// ---------------------------------------------------------------------------
__global__ __launch_bounds__(512, 2)
void g3_vwt_sm(const bf16* __restrict__ W2, const bf16* __restrict__ Xb,
               bf16* __restrict__ VWT, bf16* __restrict__ S)
{
    __shared__ __align__(16) char smem[131072];
    const int i = blockIdx.x;
    if (i < 128) {
        const int j = i >> 3;
        const int nt = (i & 7) * 4 + (j & 3);        // 0..31 (Xb panel L2-local)
        const int mt = j >> 2;                       // 0..3
        gemm256<bf16>(smem, W2, Xb, VWT, mt * 256, nt * 256, 0, 1024, 1024, 1024, 8192, 1.0f);
    } else {
        softmax_rows(S, (i - 128) * 64);
    }
}

// ---------------------------------------------------------------------------
// g4: out = P . VW (fp32 out), causal K=(mt+1)*256. R3: fence-free split-K.
// Per (b,nt) column, 12 jobs (192 blocks, all co-resident, max K=1024):
//   j0..3 : mt=j direct, K=(j+1)*256          (256..1024)
//   j4..11: mt=4+((j-4)>>1), chunk c=(j-4)&1, K halved (640/768/896/1024);
//           both chunks unsafeAtomicAdd (global_atomic_add_f32) into out
//           rows [1024,2048) which cast_all pre-zeroed. No fence, no spin.
// ---------------------------------------------------------------------------
__global__ __launch_bounds__(512, 2)
void g4_out(const bf16* __restrict__ P, const bf16* __restrict__ VWT,
            float* __restrict__ out)
{
    __shared__ __align__(16) char smem[131072];
    const int i = blockIdx.x;                        // 192
    const int r = i & 7;                             // xcd = 2b+p
    const int b = r >> 1, p = r & 1;
    const int q = i >> 3;                            // 0..23
    const int nt = p * 2 + (q & 1);
    const int j = q >> 1;                            // 0..11

    const bf16* Pp = P + (size_t)b * Ln * Ln;
    const bf16* Bv = VWT + (size_t)b * Ln;
    float* Co = out + (size_t)b * Ln * Cn;
    const int n0 = nt * 256;

    if (j < 4) {
        gemm256<float>(smem, Pp, Bv, Co, j * 256, n0, 0, (j + 1) * 256, Ln, 8192, Cn, 1.0f);
        return;
    }

    const int mt   = 4 + ((j - 4) >> 1);
    const int c    = (j - 4) & 1;
    const int half = ((mt + 1) * 256) >> 1;          // 640,768,896,1024 (÷64 ok)
    const int kb   = c * half;
    const int m0   = mt * 256;

    floatx4 acc[8][4];
    gemm256_core(smem, Pp, Bv, m0, n0, kb, kb + half, Ln, 8192, acc);

    const int lane = threadIdx.x & 63;
    const int quad = lane >> 4;
    const int lr   = lane & 15;
    const int wave = threadIdx.x >> 6;
    const int wm   = (wave >> 2) * 128;
    const int wn   = (wave & 3) * 64;

#pragma unroll
    for (int mi = 0; mi < 8; ++mi) {
        const int row = m0 + wm + mi * 16 + quad * 4;
#pragma unroll
        for (int n = 0; n < 4; ++n) {
            const int col = n0 + wn + n * 16 + lr;
            float* cp = Co + (size_t)row * Cn + col;
#pragma unroll
            for (int rr = 0; rr < 4; ++rr)
                unsafeAtomicAdd(cp + (size_t)rr * Cn, acc[mi][n][rr]);
        }
    }
}

// ---------------------------------------------------------------------------
// cast_all: blocks [0,11264)      element-wise fp32->bf16 (X, Wqk rows, Wout)
//           blocks [11264,12288)  transpose-cast Wv (1024x1024) -> WvT
//           blocks [12288,13312)  zero out rows [1024,2048) per batch (16MB)
//                                 (g4 split tiles atomicAdd into this region)
// ---------------------------------------------------------------------------
__global__ __launch_bounds__(256)
void cast_all(const float* __restrict__ X, const float* __restrict__ Wqkv,
              const float* __restrict__ Wo,
              bf16* __restrict__ Xb, bf16* __restrict__ Wqkb,
              bf16* __restrict__ Wob, bf16* __restrict__ WvT,
              float* __restrict__ out)
{
    int blk = blockIdx.x;
    if (blk < 11264) {
        int i = blk * 256 + threadIdx.x;
        const float* src; bf16* dst; int off;
        if (i < 2097152)                 { src = X;    dst = Xb;   off = i; }
        else if (i < 2097152 + 524288)   { src = Wqkv; dst = Wqkb; off = i - 2097152; }
        else                             { src = Wo;   dst = Wob;  off = i - 2621440; }
        float4 f = ((const float4*)src)[off];
        bf16 o0 = __float2bfloat16(f.x), o1 = __float2bfloat16(f.y);
        bf16 o2 = __float2bfloat16(f.z), o3 = __float2bfloat16(f.w);
        ushort4 u;
        u.x = *(unsigned short*)&o0; u.y = *(unsigned short*)&o1;
        u.z = *(unsigned short*)&o2; u.w = *(unsigned short*)&o3;
        *(ushort4*)(dst + (size_t)off * 4) = u;
    } else if (blk < 12288) {
        __shared__ float t[32][33];
        int tt = blk - 11264;
        int c0 = (tt & 31) * 32;
        int r0 = (tt >> 5) * 32;
        const float* Wv = Wqkv + 2048 * 1024;
        int xcol = threadIdx.x & 31, y0 = threadIdx.x >> 5;
#pragma unroll
        for (int p = 0; p < 4; ++p) {
            int y = y0 + 8 * p;
            t[y][xcol] = Wv[(size_t)(r0 + y) * 1024 + c0 + xcol];
        }
        __syncthreads();
#pragma unroll
        for (int p = 0; p < 4; ++p) {
            int mloc = y0 + 8 * p;
            WvT[(size_t)(c0 + mloc) * 1024 + r0 + xcol] = __float2bfloat16(t[xcol][mloc]);
        }
    } else {
        // zero split-K atomic region: per batch p, rows [1024,2048) of out
        int t = (blk - 12288) * 256 + threadIdx.x;   // 0..262143 (float4 units)
        float4* o4 = (float4*)out;
        float4 z = {0.f, 0.f, 0.f, 0.f};
#pragma unroll
        for (int p = 0; p < 4; ++p)
            o4[(size_t)p * 524288 + 262144 + t] = z;
    }
}

// ---------------------------------------------------------------------------
extern "C" void kernel_launch(void* const* d_in, const int* in_sizes, int n_in,
                              void* d_out, int out_size, void* d_ws, size_t ws_size,
                              hipStream_t stream)
{
    const float* X    = (const float*)d_in[0];   // (B,L,C)
    const float* Wqkv = (const float*)d_in[1];   // (3C,C)
    const float* Wout = (const float*)d_in[2];   // (C,C)
    float* out = (float*)d_out;                  // (B,L,C) fp32

    char* ws = (char*)d_ws;
    const size_t MiB = 1024ull * 1024ull;
    bf16* Xb   = (bf16*)(ws + 0);                // 16 MiB
    bf16* QK   = (bf16*)(ws + 16 * MiB);         // 32 MiB (q cols 0..1023, k cols 1024..2047)
    bf16* VWT  = (bf16*)(ws + 48 * MiB);         // 16 MiB (1024 x 8192, ld 8192)
    bf16* Sbuf = (bf16*)(ws + 64 * MiB);         // 32 MiB (P in place)
    bf16* Wqkb = (bf16*)(ws + 96 * MiB);         // 4 MiB
    bf16* WvT  = (bf16*)(ws + 100 * MiB);        // 2 MiB
    bf16* Wob  = (bf16*)(ws + 102 * MiB);        // 2 MiB
    bf16* W2   = (bf16*)(ws + 104 * MiB);        // 2 MiB  (total 106 MiB)

    cast_all<<<dim3(13312), 256, 0, stream>>>(X, Wqkv, Wout, Xb, Wqkb, Wob, WvT, out);

    g1_qk<<<dim3(256), 512, 0, stream>>>(Xb, Wqkb, QK);

    g2_s_w2<<<dim3(160), 512, 0, stream>>>(QK, Wob, WvT, Sbuf, W2);

    g3_vwt_sm<<<dim3(256), 512, 0, stream>>>(W2, Xb, VWT, Sbuf);

    g4_out<<<dim3(192), 512, 0, stream>>>(Sbuf, VWT, out);
}

// Round 4
// 224.011 us; speedup vs baseline: 1.4609x; 1.0686x over previous
//
#include <hip/hip_runtime.h>
#include <hip/hip_bf16.h>
#include <cstdint>
#include <cstddef>

typedef __hip_bfloat16 bf16;
typedef float  floatx4 __attribute__((ext_vector_type(4)));
typedef __bf16 bf16x8  __attribute__((ext_vector_type(8)));

typedef __attribute__((address_space(1))) void as1_void;
typedef __attribute__((address_space(3))) void as3_void;

constexpr int Bn = 4, Ln = 2048, Cn = 1024;

__device__ __forceinline__ void store_one(float* p, float v) { *p = v; }
__device__ __forceinline__ void store_one(bf16*  p, float v) { *p = __float2bfloat16(v); }

// ---------------------------------------------------------------------------
// 256x256-tile, BK=64, 8-wave (2Mx4N), 8-phase counted-vmcnt GEMM core.
// R1: SQ_LDS_BANK_CONFLICT == 0 (T2 swizzle verified).
// R2 LESSON: NO intra-kernel cross-block sync (fence+spin = coherence storm).
// R3 LESSON: 4B fp32 global atomics are ~too slow for 16.8M adds (~20us tax
// on g4) — split-K via atomics abandoned; R4 splits N instead (direct stores).
// ---------------------------------------------------------------------------
#define BAR()    asm volatile("s_barrier" ::: "memory")
#define VMCNT2() asm volatile("s_waitcnt vmcnt(2)" ::: "memory")
#define VMCNT0() asm volatile("s_waitcnt vmcnt(0)" ::: "memory")
#define SCHEDB() __builtin_amdgcn_sched_barrier(0)
#define STAGE(gp, off) \
    __builtin_amdgcn_global_load_lds((const as1_void*)(gp), (as3_void*)(smem + (off)), 16, 0, 0)

__device__ __forceinline__ void gemm256_core(
    char* __restrict__ smem,
    const bf16* __restrict__ A, const bf16* __restrict__ B,
    int m0, int n0, int kbeg, int kend, int lda, int ldb,
    floatx4 (&acc)[8][4])
{
    const int tid  = threadIdx.x;
    const int lane = tid & 63;
    const int quad = lane >> 4;
    const int lr   = lane & 15;
    const int wave = tid >> 6;
    const int wm   = (wave >> 2) * 128;   // 2 waves along M
    const int wn   = (wave & 3) * 64;     // 4 waves along N

#pragma unroll
    for (int i = 0; i < 8; ++i)
#pragma unroll
        for (int j = 0; j < 4; ++j) { floatx4 z = {0.f, 0.f, 0.f, 0.f}; acc[i][j] = z; }

    // staging: pre-swizzled global source, linear LDS dest (T2 + m104 rule)
    const int srow = tid >> 3;                    // 0..63 within a unit
    const int sx   = (tid & 7) ^ (srow & 7);      // inverse-swizzled k-slot
    const bf16* gA = A + (size_t)(m0 + srow) * lda + sx * 8 + kbeg;
    const bf16* gB = B + (size_t)(n0 + srow) * ldb + sx * 8 + kbeg;
    const int wuni = __builtin_amdgcn_readfirstlane((tid & 0x1C0) * 16); // wave*1024

    // read-side fragment offsets (elements)
    const int aoff = (wm + lr) * 64;
    const int boff = (wn + lr) * 64;
    const int s0   = (quad ^ (lr & 7)) * 8;       // kk=0 slot; kk=1 is s0^32

    const int NT = (kend - kbeg) >> 6;

    // prologue: tile 0 -> buf0; B0-3,A0,A2 (read at phase A) then A1,A3
    // (read at phase B). vmcnt(2) completes the first six.
    STAGE(gB,             32768 + 0 * 8192 + wuni);
    STAGE(gB + 64  * ldb, 32768 + 1 * 8192 + wuni);
    STAGE(gB + 128 * ldb, 32768 + 2 * 8192 + wuni);
    STAGE(gB + 192 * ldb, 32768 + 3 * 8192 + wuni);
    STAGE(gA,                     0 * 8192 + wuni);
    STAGE(gA + 128 * lda,         2 * 8192 + wuni);
    STAGE(gA + 64  * lda,         1 * 8192 + wuni);
    STAGE(gA + 192 * lda,         3 * 8192 + wuni);
    VMCNT2();
    BAR();

#define LDA4(MB, SK) do { _Pragma("unroll") for (int ii = 0; ii < 4; ++ii) \
        a[ii] = *(const bf16x8*)(As + aoff + ((MB) * 4 + ii) * 1024 + (SK)); } while (0)
#define LDB4(SK) do { _Pragma("unroll") for (int nn = 0; nn < 4; ++nn) \
        b[nn] = *(const bf16x8*)(Bs + boff + nn * 1024 + (SK)); } while (0)
#define MFMA16(MB) do { _Pragma("unroll") for (int ii = 0; ii < 4; ++ii) { \
        _Pragma("unroll") for (int nn = 0; nn < 4; ++nn) \
            acc[(MB) * 4 + ii][nn] = __builtin_amdgcn_mfma_f32_16x16x32_bf16( \
                a[ii], b[nn], acc[(MB) * 4 + ii][nn], 0, 0, 0); } } while (0)

    for (int t = 0; t < NT; ++t) {
        const bf16* As = (const bf16*)(smem + (t & 1) * 65536);
        const bf16* Bs = (const bf16*)(smem + (t & 1) * 65536 + 32768);
        const int  wl  = ((t + 1) & 1) * 65536;
        const int  kn  = (t + 1) << 6;            // relative to gA/gB (kbeg folded)
        const bool more = (t + 1 < NT);
        bf16x8 a[4], b[4];

        // ---- phase A: mi0-3, kk0 ----
        LDB4(s0);
        LDA4(0, s0);
        if (more) {
            STAGE(gB + kn,            wl + 32768 + 0 * 8192 + wuni);
            STAGE(gB + kn + 64 * ldb, wl + 32768 + 1 * 8192 + wuni);
        }
        BAR(); SCHEDB();
        __builtin_amdgcn_s_setprio(1);
        MFMA16(0);
        __builtin_amdgcn_s_setprio(0);
        SCHEDB();
        if (more) VMCNT2(); else VMCNT0();   // A1,A3 of tile t now resident
        BAR();

        // ---- phase B: mi4-7, kk0 ----
        LDA4(1, s0);
        if (more) {
            STAGE(gB + kn + 128 * ldb, wl + 32768 + 2 * 8192 + wuni);
            STAGE(gB + kn + 192 * ldb, wl + 32768 + 3 * 8192 + wuni);
        }
        BAR(); SCHEDB();
        __builtin_amdgcn_s_setprio(1);
        MFMA16(1);
        __builtin_amdgcn_s_setprio(0);
        SCHEDB();
        BAR();

        // ---- phase C: mi0-3, kk1 ----
        LDB4(s0 ^ 32);
        LDA4(0, s0 ^ 32);
        if (more) {
            STAGE(gA + kn,             wl + 0 * 8192 + wuni);
            STAGE(gA + kn + 128 * lda, wl + 2 * 8192 + wuni);
        }
        BAR(); SCHEDB();
        __builtin_amdgcn_s_setprio(1);
        MFMA16(0);
        __builtin_amdgcn_s_setprio(0);
        SCHEDB();
        BAR();

        // ---- phase D: mi4-7, kk1 ----
        LDA4(1, s0 ^ 32);
        if (more) {
            STAGE(gA + kn + 64  * lda, wl + 1 * 8192 + wuni);
            STAGE(gA + kn + 192 * lda, wl + 3 * 8192 + wuni);
        }
        BAR(); SCHEDB();
        __builtin_amdgcn_s_setprio(1);
        MFMA16(1);
        __builtin_amdgcn_s_setprio(0);
        SCHEDB();
        if (more) VMCNT2();                  // B0-3,A0,A2 of tile t+1 resident
        BAR();
    }
#undef LDA4
#undef LDB4
#undef MFMA16
}

template <typename OutT>
__device__ __forceinline__ void gemm256(
    char* __restrict__ smem,
    const bf16* __restrict__ A, const bf16* __restrict__ B, OutT* __restrict__ C,
    int m0, int n0, int kbeg, int kend, int lda, int ldb, int ldc, float cscale)
{
    floatx4 acc[8][4];
    gemm256_core(smem, A, B, m0, n0, kbeg, kend, lda, ldb, acc);

    const int lane = threadIdx.x & 63;
    const int quad = lane >> 4;
    const int lr   = lane & 15;
    const int wave = threadIdx.x >> 6;
    const int wm   = (wave >> 2) * 128;
    const int wn   = (wave & 3) * 64;

    // C/D layout col=lane&15, row=quad*4+r (m89-verified)
#pragma unroll
    for (int mi = 0; mi < 8; ++mi) {
        const int row = m0 + wm + mi * 16 + quad * 4;
#pragma unroll
        for (int n = 0; n < 4; ++n) {
            const int col = n0 + wn + n * 16 + lr;
            OutT* cp = C + (size_t)row * ldc + col;
#pragma unroll
            for (int r = 0; r < 4; ++r)
                store_one(cp + (size_t)r * ldc, acc[mi][n][r] * cscale);
        }
    }
}

// ---------------------------------------------------------------------------
// R4: 256(M)x128(N)-tile sibling core for g4 (direct stores, no atomics).
// Same swizzle/phase ladder; acc[8][2]; A = 4 units, B = 2 units (48KB/tile,
// 96KB LDS). vmcnt ledger: prologue {B0,B1,A0,A2}+{A1,A3} wait(2); per tile
// issue B0',B1' @A / A0',A2' @B / A1',A3' @C / none @D; waits end-A (A1,A3 of
// t -> vmcnt(2), last tile vmcnt(0)) and end-D (B0',B1',A0',A2' -> vmcnt(2)).
// ---------------------------------------------------------------------------
__device__ __forceinline__ void gemm_pv_128n(
    char* __restrict__ smem,
    const bf16* __restrict__ A, const bf16* __restrict__ B, float* __restrict__ C,
    int m0, int n0, int kend, int lda, int ldb, int ldc)
{
    const int tid  = threadIdx.x;
    const int lane = tid & 63;
    const int quad = lane >> 4;
    const int lr   = lane & 15;
    const int wave = tid >> 6;
    const int wm   = (wave >> 2) * 128;   // 2 waves along M (rows 0/128)
    const int wn   = (wave & 3) * 32;     // 4 waves along N (32 cols each)

    floatx4 acc[8][2];
#pragma unroll
    for (int i = 0; i < 8; ++i)
#pragma unroll
        for (int j = 0; j < 2; ++j) { floatx4 z = {0.f, 0.f, 0.f, 0.f}; acc[i][j] = z; }

    const int srow = tid >> 3;
    const int sx   = (tid & 7) ^ (srow & 7);
    const bf16* gA = A + (size_t)(m0 + srow) * lda + sx * 8;
    const bf16* gB = B + (size_t)(n0 + srow) * ldb + sx * 8;
    const int wuni = __builtin_amdgcn_readfirstlane((tid & 0x1C0) * 16);

    const int aoff = (wm + lr) * 64;
    const int boff = (wn + lr) * 64;
    const int s0   = (quad ^ (lr & 7)) * 8;

    const int NT = kend >> 6;
    const int BUF = 49152;                 // 32KB A + 16KB B per buffer

    // prologue: B0,B1,A0,A2 (phase-A needs) then A1,A3 (phase-B needs)
    STAGE(gB,             32768 + 0 * 8192 + wuni);
    STAGE(gB + 64  * ldb, 32768 + 1 * 8192 + wuni);
    STAGE(gA,                     0 * 8192 + wuni);
    STAGE(gA + 128 * lda,         2 * 8192 + wuni);
    STAGE(gA + 64  * lda,         1 * 8192 + wuni);
    STAGE(gA + 192 * lda,         3 * 8192 + wuni);
    VMCNT2();
    BAR();

#define LDA4(MB, SK) do { _Pragma("unroll") for (int ii = 0; ii < 4; ++ii) \
        a[ii] = *(const bf16x8*)(As + aoff + ((MB) * 4 + ii) * 1024 + (SK)); } while (0)
#define LDB2(SK) do { _Pragma("unroll") for (int nn = 0; nn < 2; ++nn) \
        b[nn] = *(const bf16x8*)(Bs + boff + nn * 1024 + (SK)); } while (0)
#define MFMA8(MB) do { _Pragma("unroll") for (int ii = 0; ii < 4; ++ii) { \
        _Pragma("unroll") for (int nn = 0; nn < 2; ++nn) \
            acc[(MB) * 4 + ii][nn] = __builtin_amdgcn_mfma_f32_16x16x32_bf16( \
                a[ii], b[nn], acc[(MB) * 4 + ii][nn], 0, 0, 0); } } while (0)

    for (int t = 0; t < NT; ++t) {
        const bf16* As = (const bf16*)(smem + (t & 1) * BUF);
        const bf16* Bs = (const bf16*)(smem + (t & 1) * BUF + 32768);
        const int  wl  = ((t + 1) & 1) * BUF;
        const int  kn  = (t + 1) << 6;
        const bool more = (t + 1 < NT);
        bf16x8 a[4], b[2];

        // ---- phase A: mi0-3, kk0 ----
        LDB2(s0);
        LDA4(0, s0);
        if (more) {
            STAGE(gB + kn,            wl + 32768 + 0 * 8192 + wuni);
            STAGE(gB + kn + 64 * ldb, wl + 32768 + 1 * 8192 + wuni);
        }
        BAR(); SCHEDB();
        __builtin_amdgcn_s_setprio(1);
        MFMA8(0);
        __builtin_amdgcn_s_setprio(0);
        SCHEDB();
        if (more) VMCNT2(); else VMCNT0();   // A1,A3 of tile t resident
        BAR();

        // ---- phase B: mi4-7, kk0 ----
        LDA4(1, s0);
        if (more) {
            STAGE(gA + kn,             wl + 0 * 8192 + wuni);
            STAGE(gA + kn + 128 * lda, wl + 2 * 8192 + wuni);
        }
        BAR(); SCHEDB();
        __builtin_amdgcn_s_setprio(1);
        MFMA8(1);
        __builtin_amdgcn_s_setprio(0);
        SCHEDB();
        BAR();

        // ---- phase C: mi0-3, kk1 ----
        LDB2(s0 ^ 32);
        LDA4(0, s0 ^ 32);
        if (more) {
            STAGE(gA + kn + 64  * lda, wl + 1 * 8192 + wuni);
            STAGE(gA + kn + 192 * lda, wl + 3 * 8192 + wuni);
        }
        BAR(); SCHEDB();
        __builtin_amdgcn_s_setprio(1);
        MFMA8(0);
        __builtin_amdgcn_s_setprio(0);
        SCHEDB();
        BAR();

        // ---- phase D: mi4-7, kk1 ----
        LDA4(1, s0 ^ 32);
        BAR(); SCHEDB();
        __builtin_amdgcn_s_setprio(1);
        MFMA8(1);
        __builtin_amdgcn_s_setprio(0);
        SCHEDB();
        if (more) VMCNT2();                  // B0,B1,A0,A2 of tile t+1 resident
        BAR();
    }
#undef LDA4
#undef LDB2
#undef MFMA8

#pragma unroll
    for (int mi = 0; mi < 8; ++mi) {
        const int row = m0 + wm + mi * 16 + quad * 4;
#pragma unroll
        for (int n = 0; n < 2; ++n) {
            const int col = n0 + wn + n * 16 + lr;
            float* cp = C + (size_t)row * ldc + col;
#pragma unroll
            for (int r = 0; r < 4; ++r)
                cp[(size_t)r * ldc] = acc[mi][n][r];
        }
    }
}

// ---------------------------------------------------------------------------
// g1: QK = Xb . Wqkb^T  (8192x2048, K=1024) -> 32x8 = 256 blocks (1 full wave)
// ---------------------------------------------------------------------------
__global__ __launch_bounds__(512, 2)
void g1_qk(const bf16* __restrict__ Xb, const bf16* __restrict__ Wqkb,
           bf16* __restrict__ QK)
{
    __shared__ __align__(16) char smem[131072];
    const int i = blockIdx.x;
    const int j = i >> 3;
    const int mt = (i & 7) * 4 + (j & 3);
    const int nt = j >> 2;
    gemm256<bf16>(smem, Xb, Wqkb, QK, mt * 256, nt * 256, 0, 1024, 1024, 1024, 2048, 1.0f);
}

// ---------------------------------------------------------------------------
// g2: blocks [0,144)  -> S = (Q.K^T)/32, triangular 256-tiles, 36/batch.
//     blocks [144,160) -> W2 = Wo.Wv (1024^2, K=1024).
// ---------------------------------------------------------------------------
__global__ __launch_bounds__(512, 2)
void g2_s_w2(const bf16* __restrict__ QK, const bf16* __restrict__ Wob,
             const bf16* __restrict__ WvT, bf16* __restrict__ S,
             bf16* __restrict__ W2)
{
    __shared__ __align__(16) char smem[131072];
    const int i = blockIdx.x;
    if (i < 144) {
        const int b = (i & 7) >> 1;
        const int t = (i >> 3) * 2 + (i & 1);        // 0..35
        int ti = (int)((sqrtf(8.f * t + 1.f) - 1.f) * 0.5f);
        while ((ti + 1) * (ti + 2) / 2 <= t) ++ti;
        while (ti * (ti + 1) / 2 > t) --ti;
        const int tj = t - ti * (ti + 1) / 2;
        const bf16* Aq = QK + (size_t)b * Ln * 2048;
        const bf16* Bk = Aq + 1024;
        bf16* Sb = S + (size_t)b * Ln * Ln;
        gemm256<bf16>(smem, Aq, Bk, Sb, ti * 256, tj * 256, 0, 1024, 2048, 2048, Ln, 0.03125f);
    } else {
        const int j = i - 144;
        gemm256<bf16>(smem, Wob, WvT, W2, (j & 3) * 256, (j >> 2) * 256, 0, 1024, 1024, 1024, 1024, 1.0f);
    }
}

// ---------------------------------------------------------------------------
// softmax rows (one wave per row, no barriers) — fused into g3.
// ---------------------------------------------------------------------------
__device__ __forceinline__ float waveMax(float x) {
#pragma unroll
    for (int o = 32; o > 0; o >>= 1) x = fmaxf(x, __shfl_xor(x, o, 64));
    return x;
}
__device__ __forceinline__ float waveSum(float x) {
#pragma unroll
    for (int o = 32; o > 0; o >>= 1) x += __shfl_xor(x, o, 64);
    return x;
}

__device__ void softmax_rows(bf16* __restrict__ S, int row0)
{
    const int wave = threadIdx.x >> 6, lane = threadIdx.x & 63;
    for (int it8 = 0; it8 < 8; ++it8) {
        const int row = row0 + wave * 8 + it8;       // 0..8191 = b*L + q
        const int q = row & (Ln - 1);
        bf16* Srow = S + (size_t)row * Ln;
        const int kmax = ((q >> 7) + 1) << 7;
        const int nv = (kmax + 511) >> 9;            // 1..4 chunks of 512 cols
        float x[4][8];
        float m = -1e30f;
        for (int it = 0; it < nv; ++it) {
            int c0 = it * 512 + lane * 8;
            bf16x8 v = *(const bf16x8*)(Srow + c0);
#pragma unroll
            for (int e = 0; e < 8; ++e) {
                float f = (float)v[e];
                f = (c0 + e <= q) ? f : -1e30f;
                x[it][e] = f;
                m = fmaxf(m, f);
            }
        }
        m = waveMax(m);
        float s = 0.f;
        for (int it = 0; it < nv; ++it)
#pragma unroll
            for (int e = 0; e < 8; ++e) {
                float ex = (x[it][e] > -1e29f) ? __expf(x[it][e] - m) : 0.f;
                x[it][e] = ex;
                s += ex;
            }
        s = waveSum(s);
        const float inv = 1.f / s;
        for (int it = 0; it < nv; ++it) {
            bf16x8 o;
#pragma unroll
            for (int e = 0; e < 8; ++e) o[e] = (__bf16)(x[it][e] * inv);
            *(bf16x8*)(Srow + it * 512 + lane * 8) = o;
        }
    }
}

// ---------------------------------------------------------------------------
// g3: blocks [0,128)   -> VWT = W2 . Xb^T (1024x8192, ldc 8192); needs W2.
//     blocks [128,256) -> causal softmax on S (64 rows/block); needs all S.
// ---------------------------------------------------------------------------
__global__ __launch_bounds__(512, 2)
void g3_vwt_sm(const bf16* __restrict__ W2, const bf16* __restrict__ Xb,
               bf16* __restrict__ VWT, bf16* __restrict__ S)
{
    __shared__ __align__(16) char smem[131072];
    const int i = blockIdx.x;
    if (i < 128) {
        const int j = i >> 3;
        const int nt = (i & 7) * 4 + (j & 3);        // 0..31 (Xb panel L2-local)
        const int mt = j >> 2;                       // 0..3
        gemm256<bf16>(smem, W2, Xb, VWT, mt * 256, nt * 256, 0, 1024, 1024, 1024, 8192, 1.0f);
    } else {
        softmax_rows(S, (i - 128) * 64);
    }
}

// ---------------------------------------------------------------------------
// g4: out = P . VW (fp32), R4: 256x128 tiles, 8mt x 8nt x 4b = 256 blocks,
// all direct stores, K=(mt+1)*256. XCD i&7 = 2b+p pins batch to XCD pair.
// ---------------------------------------------------------------------------
__global__ __launch_bounds__(512, 2)
void g4_out(const bf16* __restrict__ P, const bf16* __restrict__ VWT,
            float* __restrict__ out)
{
    __shared__ __align__(16) char smem[98304];
    const int i = blockIdx.x;                        // 256
    const int r = i & 7;
    const int b = r >> 1, p = r & 1;
    const int q = i >> 3;                            // 0..31
    const int nt = p * 4 + (q & 3);                  // 0..7 (128-wide)
    const int mt = q >> 2;                           // 0..7

    const bf16* Pp = P + (size_t)b * Ln * Ln;
    const bf16* Bv = VWT + (size_t)b * Ln;
    float* Co = out + (size_t)b * Ln * Cn;
    gemm_pv_128n(smem, Pp, Bv, Co, mt * 256, nt * 128, (mt + 1) * 256, Ln, 8192, Cn);
}

// ---------------------------------------------------------------------------
// cast_all: blocks [0,11264)      element-wise fp32->bf16 (X, Wqk rows, Wout)
//           blocks [11264,12288)  transpose-cast Wv (1024x1024) -> WvT
// ---------------------------------------------------------------------------
__global__ __launch_bounds__(256)
void cast_all(const float* __restrict__ X, const float* __restrict__ Wqkv,
              const float* __restrict__ Wo,
              bf16* __restrict__ Xb, bf16* __restrict__ Wqkb,
              bf16* __restrict__ Wob, bf16* __restrict__ WvT)
{
    int blk = blockIdx.x;
    if (blk < 11264) {
        int i = blk * 256 + threadIdx.x;
        const float* src; bf16* dst; int off;
        if (i < 2097152)                 { src = X;    dst = Xb;   off = i; }
        else if (i < 2097152 + 524288)   { src = Wqkv; dst = Wqkb; off = i - 2097152; }
        else                             { src = Wo;   dst = Wob;  off = i - 2621440; }
        float4 f = ((const float4*)src)[off];
        bf16 o0 = __float2bfloat16(f.x), o1 = __float2bfloat16(f.y);
        bf16 o2 = __float2bfloat16(f.z), o3 = __float2bfloat16(f.w);
        ushort4 u;
        u.x = *(unsigned short*)&o0; u.y = *(unsigned short*)&o1;
        u.z = *(unsigned short*)&o2; u.w = *(unsigned short*)&o3;
        *(ushort4*)(dst + (size_t)off * 4) = u;
    } else {
        __shared__ float t[32][33];
        int tt = blk - 11264;
        int c0 = (tt & 31) * 32;
        int r0 = (tt >> 5) * 32;
        const float* Wv = Wqkv + 2048 * 1024;
        int xcol = threadIdx.x & 31, y0 = threadIdx.x >> 5;
#pragma unroll
        for (int p = 0; p < 4; ++p) {
            int y = y0 + 8 * p;
            t[y][xcol] = Wv[(size_t)(r0 + y) * 1024 + c0 + xcol];
        }
        __syncthreads();
#pragma unroll
        for (int p = 0; p < 4; ++p) {
            int mloc = y0 + 8 * p;
            WvT[(size_t)(c0 + mloc) * 1024 + r0 + xcol] = __float2bfloat16(t[xcol][mloc]);
        }
    }
}

// ---------------------------------------------------------------------------
extern "C" void kernel_launch(void* const* d_in, const int* in_sizes, int n_in,
                              void* d_out, int out_size, void* d_ws, size_t ws_size,
                              hipStream_t stream)
{
    const float* X    = (const float*)d_in[0];   // (B,L,C)
    const float* Wqkv = (const float*)d_in[1];   // (3C,C)
    const float* Wout = (const float*)d_in[2];   // (C,C)
    float* out = (float*)d_out;                  // (B,L,C) fp32

    char* ws = (char*)d_ws;
    const size_t MiB = 1024ull * 1024ull;
    bf16* Xb   = (bf16*)(ws + 0);                // 16 MiB
    bf16* QK   = (bf16*)(ws + 16 * MiB);         // 32 MiB (q cols 0..1023, k cols 1024..2047)
    bf16* VWT  = (bf16*)(ws + 48 * MiB);         // 16 MiB (1024 x 8192, ld 8192)
    bf16* Sbuf = (bf16*)(ws + 64 * MiB);         // 32 MiB (P in place)
    bf16* Wqkb = (bf16*)(ws + 96 * MiB);         // 4 MiB
    bf16* WvT  = (bf16*)(ws + 100 * MiB);        // 2 MiB
    bf16* Wob  = (bf16*)(ws + 102 * MiB);        // 2 MiB
    bf16* W2   = (bf16*)(ws + 104 * MiB);        // 2 MiB  (total 106 MiB)

    cast_all<<<dim3(12288), 256, 0, stream>>>(X, Wqkv, Wout, Xb, Wqkb, Wob, WvT);

    g1_qk<<<dim3(256), 512, 0, stream>>>(Xb, Wqkb, QK);

    g2_s_w2<<<dim3(160), 512, 0, stream>>>(QK, Wob, WvT, Sbuf, W2);

    g3_vwt_sm<<<dim3(256), 512, 0, stream>>>(W2, Xb, VWT, Sbuf);

    g4_out<<<dim3(256), 512, 0, stream>>>(Sbuf, VWT, out);
}